// Round 1
// baseline (196.172 us; speedup 1.0000x reference)
//
#include <hip/hip_runtime.h>
#include <hip/hip_bf16.h>
#include <stdint.h>

#define BATCH 8192
#define PEP 15
#define INC 512
#define OUTC 512
#define XROW (PEP*INC)          // 7680 floats per batch row
#define BM 64
#define BK 32
#define NSTEPS (INC/BK)         // 16

typedef float f32x4 __attribute__((ext_vector_type(4)));
typedef short s16x8 __attribute__((ext_vector_type(8)));

__device__ __forceinline__ ushort f2b(float v) {
  // round-to-nearest-even fp32 -> bf16 (inputs are finite normals)
  uint u = __float_as_uint(v);
  u += 0x7fffu + ((u >> 16) & 1u);
  return (ushort)(u >> 16);
}

// ---------------- kernel 1: W [p][k][n] fp32 -> Wt [p][n][k] bf16 ----------------
__global__ __launch_bounds__(256) void wt_kernel(const float* __restrict__ w,
                                                 ushort* __restrict__ wt) {
  int gid = blockIdx.x * 256 + threadIdx.x;   // 15*512*32 = 245760 exactly
  int n  = gid & 511;                         // fastest -> coalesced reads
  int kc = (gid >> 9) & 31;                   // 32 chunks of 16 k
  int p  = gid >> 14;                         // 0..14
  const float* src = w + (size_t)p * (INC * OUTC) + (size_t)(kc * 16) * OUTC + n;
  ushort h[16];
#pragma unroll
  for (int j = 0; j < 16; ++j) h[j] = f2b(src[(size_t)j * OUTC]);
  ushort* dst = wt + (size_t)p * (OUTC * INC) + (size_t)n * INC + kc * 16;
  s16x8 a, b;
#pragma unroll
  for (int j = 0; j < 8; ++j) { a[j] = (short)h[j]; b[j] = (short)h[j + 8]; }
  *(s16x8*)dst = a;
  *(s16x8*)(dst + 8) = b;
}

// ---------------- kernel 2: per-p GEMM, BM=64 x BN=512, 4 waves ----------------
__global__ __launch_bounds__(256, 2) void gemm_kernel(const float* __restrict__ x,
                                                      const ushort* __restrict__ wt,
                                                      const float* __restrict__ bias,
                                                      float* __restrict__ out) {
  __shared__ ushort As[BM][BK + 8];   // 64 x 40, +8 pad vs bank conflicts (80B rows, 16B-aligned)
  __shared__ ushort Bs[OUTC][BK];     // 512 x 32, LINEAR (global_load_lds dest)

  const int t    = threadIdx.x;
  const int lane = t & 63;
  const int wid  = t >> 6;            // 0..3, wave owns n-cols [wid*128, +128)
  const int fr   = lane & 15;
  const int g    = lane >> 4;

  const int p  = blockIdx.z;
  const int m0 = blockIdx.x * BM;

  f32x4 acc[4][8] = {};               // 4 m-frags x 8 n-frags of 16x16

  // A staging: thread -> row ar, 8 floats at col ac
  const int ar = t >> 2;              // 0..63
  const int ac = (t & 3) * 8;         // 0,8,16,24
  const float* a_src = x + (size_t)(m0 + ar) * XROW + p * INC + ac;

  // B staging: wave wid stages Bs rows [wid*128, +128) via 8 global_load_lds (16B/lane)
  const ushort* wt_p  = wt + (size_t)p * (OUTC * INC);
  const ushort* b_src = wt_p + (size_t)(wid * 128 + (lane >> 2)) * INC + (lane & 3) * 8;
  ushort* bs_base = &Bs[wid * 128][0];

  for (int ks = 0; ks < NSTEPS; ++ks) {
    // issue A global loads early (regs; no LDS hazard)
    f32x4 v0 = *(const f32x4*)(a_src + ks * BK);
    f32x4 v1 = *(const f32x4*)(a_src + ks * BK + 4);

    __syncthreads();  // all waves done reading previous tile

    // B: global -> LDS direct, 8 issues of 16 rows x 64B
#pragma unroll
    for (int q = 0; q < 8; ++q) {
      __builtin_amdgcn_global_load_lds(
          (const __attribute__((address_space(1))) void*)(b_src + q * 16 * INC + ks * BK),
          (__attribute__((address_space(3))) void*)(bs_base + q * 16 * BK),
          16, 0, 0);
    }

    // A: cvt fp32 -> bf16, one ds_write_b128 per thread
    s16x8 hv;
    hv[0] = (short)f2b(v0[0]); hv[1] = (short)f2b(v0[1]);
    hv[2] = (short)f2b(v0[2]); hv[3] = (short)f2b(v0[3]);
    hv[4] = (short)f2b(v1[0]); hv[5] = (short)f2b(v1[1]);
    hv[6] = (short)f2b(v1[2]); hv[7] = (short)f2b(v1[3]);
    *(s16x8*)&As[ar][ac] = hv;

    __syncthreads();  // staging complete (compiler drains vmcnt+lgkm before barrier)

    s16x8 af[4], bfv[8];
#pragma unroll
    for (int mf = 0; mf < 4; ++mf)
      af[mf] = *(const s16x8*)&As[mf * 16 + fr][g * 8];
#pragma unroll
    for (int nf = 0; nf < 8; ++nf)
      bfv[nf] = *(const s16x8*)&Bs[wid * 128 + nf * 16 + fr][g * 8];
#pragma unroll
    for (int mf = 0; mf < 4; ++mf)
#pragma unroll
      for (int nf = 0; nf < 8; ++nf)
        acc[mf][nf] = __builtin_amdgcn_mfma_f32_16x16x32_bf16(af[mf], bfv[nf], acc[mf][nf], 0, 0, 0);
  }

  // epilogue: C/D layout col=lane&15, row=(lane>>4)*4+r  (m89-verified)
  float bv[8];
#pragma unroll
  for (int nf = 0; nf < 8; ++nf) bv[nf] = bias[p * OUTC + wid * 128 + nf * 16 + fr];

  float* op = out + (size_t)(m0 + g * 4) * XROW + p * INC + wid * 128;
#pragma unroll
  for (int mf = 0; mf < 4; ++mf)
#pragma unroll
    for (int nf = 0; nf < 8; ++nf)
#pragma unroll
      for (int r = 0; r < 4; ++r)
        op[(size_t)(mf * 16 + r) * XROW + nf * 16 + fr] = acc[mf][nf][r] + bv[nf];
}

// ---------------- fallback (only if ws too small): naive fp32 ----------------
__global__ void naive_kernel(const float* __restrict__ x, const float* __restrict__ w,
                             const float* __restrict__ bias, float* __restrict__ out) {
  size_t i = (size_t)blockIdx.x * 256 + threadIdx.x;
  if (i >= (size_t)BATCH * PEP * OUTC) return;
  int o  = (int)(i & (OUTC - 1));
  int pp = (int)((i >> 9) % PEP);
  size_t b = i / ((size_t)PEP * OUTC);
  const float* xr = x + b * XROW + pp * INC;
  const float* wc = w + (size_t)pp * INC * OUTC + o;
  float s = bias[pp * OUTC + o];
  for (int k = 0; k < INC; ++k) s += xr[k] * wc[(size_t)k * OUTC];
  out[i] = s;
}

extern "C" void kernel_launch(void* const* d_in, const int* in_sizes, int n_in,
                              void* d_out, int out_size, void* d_ws, size_t ws_size,
                              hipStream_t stream) {
  const float* x    = (const float*)d_in[0];
  const float* w    = (const float*)d_in[1];
  const float* bias = (const float*)d_in[2];
  float* out = (float*)d_out;

  const size_t wt_bytes = (size_t)PEP * INC * OUTC * sizeof(ushort);  // 7.9 MB
  if (ws_size >= wt_bytes) {
    wt_kernel<<<960, 256, 0, stream>>>(w, (ushort*)d_ws);
    dim3 grid(BATCH / BM, 1, PEP);
    gemm_kernel<<<grid, 256, 0, stream>>>(x, (const ushort*)d_ws, bias, out);
  } else {
    size_t total = (size_t)BATCH * PEP * OUTC;
    naive_kernel<<<(int)((total + 255) / 256), 256, 0, stream>>>(x, w, bias, out);
  }
}